// Round 1
// baseline (2571.748 us; speedup 1.0000x reference)
//
#include <hip/hip_runtime.h>
#include <cstdint>

#define HID2 128
#define CSZ  144

// 2 waves / block. Wave w handles hidden-dim half w of rows [blk*64, blk*64+64).
// Weight indices are wave-uniform -> scalar (SGPR) loads; activations per-lane.
__global__ __launch_bounds__(128, 2)
void mmse_mlp(const float* __restrict__ xr, const float* __restrict__ xi,
              const float* __restrict__ W1, const float* __restrict__ b1,
              const float* __restrict__ g1, const float* __restrict__ be1,
              const float* __restrict__ W2, const float* __restrict__ b2,
              const float* __restrict__ g2, const float* __restrict__ be2,
              const float* __restrict__ W3, const float* __restrict__ b3,
              const float* __restrict__ W4, const float* __restrict__ b4,
              float* __restrict__ outLr, float* __restrict__ outLi)
{
    constexpr int PITCH = 145;              // odd pitch: bank = (17*l + c) % 32, conflict-free
    __shared__ float hb[64][PITCH];         // x / h1 / h2 / h3 / f / output staging
    __shared__ float lnb[2][64][2];         // LN partial (sum, sumsq) exchange

    const int tid  = threadIdx.x;
    const int lane = tid & 63;
    const int half = __builtin_amdgcn_readfirstlane(tid >> 6);  // wave-uniform
    const int64_t rowg = (int64_t)blockIdx.x * 64 + lane;

    // ---- stage x = concat(real, imag) into hb[lane][0..23] (wave 0 only) ----
    if (half == 0) {
        const float4* pr = reinterpret_cast<const float4*>(xr + rowg * 12);
        const float4* pi = reinterpret_cast<const float4*>(xi + rowg * 12);
        #pragma unroll
        for (int c = 0; c < 3; ++c) {
            float4 v = pr[c];
            hb[lane][4*c+0] = v.x; hb[lane][4*c+1] = v.y;
            hb[lane][4*c+2] = v.z; hb[lane][4*c+3] = v.w;
        }
        #pragma unroll
        for (int c = 0; c < 3; ++c) {
            float4 v = pi[c];
            hb[lane][12+4*c+0] = v.x; hb[lane][12+4*c+1] = v.y;
            hb[lane][12+4*c+2] = v.z; hb[lane][12+4*c+3] = v.w;
        }
    }
    __syncthreads();

    float acc[72];  // widest layer output per thread (layer4: 72)

    // ---------------- layer 1: 24 -> 128, LN, lrelu ----------------
    {
        const int jb = half * 64;
        #pragma unroll
        for (int j = 0; j < 64; ++j) acc[j] = b1[jb + j];
        for (int k = 0; k < 24; ++k) {
            const float hk = hb[lane][k];
            const float* __restrict__ wr = W1 + k * HID2 + jb;   // uniform addr
            #pragma unroll
            for (int j = 0; j < 64; ++j) acc[j] = fmaf(hk, wr[j], acc[j]);
        }
        float s = 0.f, s2 = 0.f;
        #pragma unroll
        for (int j = 0; j < 64; ++j) { s += acc[j]; s2 += acc[j] * acc[j]; }
        lnb[half][lane][0] = s; lnb[half][lane][1] = s2;
        __syncthreads();
        s  += lnb[half ^ 1][lane][0];
        s2 += lnb[half ^ 1][lane][1];
        const float mean = s * (1.f / 128.f);
        const float var  = s2 * (1.f / 128.f) - mean * mean;
        const float rstd = 1.f / sqrtf(var + 1e-5f);
        #pragma unroll
        for (int j = 0; j < 64; ++j) {
            float h = (acc[j] - mean) * rstd * g1[jb + j] + be1[jb + j];
            h = (h >= 0.f) ? h : 0.1f * h;
            hb[lane][jb + j] = h;
        }
        __syncthreads();
    }

    // ---------------- layer 2: 128 -> 128, LN, lrelu ----------------
    {
        const int jb = half * 64;
        #pragma unroll
        for (int j = 0; j < 64; ++j) acc[j] = b2[jb + j];
        for (int k = 0; k < 128; ++k) {
            const float hk = hb[lane][k];
            const float* __restrict__ wr = W2 + k * HID2 + jb;
            #pragma unroll
            for (int j = 0; j < 64; ++j) acc[j] = fmaf(hk, wr[j], acc[j]);
        }
        float s = 0.f, s2 = 0.f;
        #pragma unroll
        for (int j = 0; j < 64; ++j) { s += acc[j]; s2 += acc[j] * acc[j]; }
        __syncthreads();   // all layer-2 reads of hb done; lnb reuse safe
        lnb[half][lane][0] = s; lnb[half][lane][1] = s2;
        __syncthreads();
        s  += lnb[half ^ 1][lane][0];
        s2 += lnb[half ^ 1][lane][1];
        const float mean = s * (1.f / 128.f);
        const float var  = s2 * (1.f / 128.f) - mean * mean;
        const float rstd = 1.f / sqrtf(var + 1e-5f);
        #pragma unroll
        for (int j = 0; j < 64; ++j) {
            float h = (acc[j] - mean) * rstd * g2[jb + j] + be2[jb + j];
            h = (h >= 0.f) ? h : 0.1f * h;
            hb[lane][jb + j] = h;
        }
        __syncthreads();
    }

    // ---------------- layer 3: 128 -> 64, lrelu ----------------
    {
        const int jb = half * 32;
        #pragma unroll
        for (int j = 0; j < 32; ++j) acc[j] = b3[jb + j];
        for (int k = 0; k < 128; ++k) {
            const float hk = hb[lane][k];
            const float* __restrict__ wr = W3 + k * 64 + jb;
            #pragma unroll
            for (int j = 0; j < 32; ++j) acc[j] = fmaf(hk, wr[j], acc[j]);
        }
        __syncthreads();   // everyone done reading h2
        #pragma unroll
        for (int j = 0; j < 32; ++j) {
            float h = acc[j];
            h = (h >= 0.f) ? h : 0.1f * h;
            hb[lane][jb + j] = h;
        }
        __syncthreads();
    }

    // ---------------- layer 4: 64 -> 144 ----------------
    {
        const int jb = half * 72;
        #pragma unroll
        for (int j = 0; j < 72; ++j) acc[j] = b4[jb + j];
        for (int k = 0; k < 64; ++k) {
            const float hk = hb[lane][k];
            const float* __restrict__ wr = W4 + k * CSZ + jb;
            #pragma unroll
            for (int j = 0; j < 72; ++j) acc[j] = fmaf(hk, wr[j], acc[j]);
        }
        __syncthreads();   // everyone done reading h3
        #pragma unroll
        for (int j = 0; j < 72; ++j) hb[lane][jb + j] = acc[j];  // stage f[144]
        __syncthreads();
    }

    // ---------------- build L (Lr, Li) and write coalesced ----------------
    {
        const int64_t base = (int64_t)blockIdx.x * 64 * CSZ;
        #pragma unroll
        for (int mat = 0; mat < 2; ++mat) {
            float* __restrict__ op = (mat == 0) ? (outLr + base) : (outLi + base);
            const int ob = (mat == 0) ? 12 : 78;   // strict-lower factor base
            #pragma unroll
            for (int u = 0; u < 18; ++u) {
                const int t4 = tid + u * 128;        // 0..2303 float4 units
                const int r  = t4 / 36;              // row within block
                const int cc = (t4 - r * 36) * 4;    // column (0..143)
                float vv[4];
                #pragma unroll
                for (int e = 0; e < 4; ++e) {
                    const int c = cc + e;
                    const int i = c / 12;
                    const int j = c - i * 12;
                    float val = 0.f;
                    if (i > j)                       val = hb[r][ob + (i * (i - 1)) / 2 + j];
                    else if (i == j && mat == 0)     val = hb[r][i];   // Lr diag
                    vv[e] = val;
                }
                float4 v; v.x = vv[0]; v.y = vv[1]; v.z = vv[2]; v.w = vv[3];
                reinterpret_cast<float4*>(op)[t4] = v;
            }
        }
    }
}

extern "C" void kernel_launch(void* const* d_in, const int* in_sizes, int n_in,
                              void* d_out, int out_size, void* d_ws, size_t ws_size,
                              hipStream_t stream)
{
    const float* xr = (const float*)d_in[0];
    const float* xi = (const float*)d_in[1];
    float* out = (float*)d_out;
    const int64_t MAT = (int64_t)262144 * CSZ;

    for (int m = 0; m < 2; ++m) {        // m=0: C-MLP (mats 0,1), m=1: R-MLP (mats 2,3)
        const int o = 2 + m * 12;
        mmse_mlp<<<4096, 128, 0, stream>>>(
            xr, xi,
            (const float*)d_in[o + 0],  (const float*)d_in[o + 1],
            (const float*)d_in[o + 2],  (const float*)d_in[o + 3],
            (const float*)d_in[o + 4],  (const float*)d_in[o + 5],
            (const float*)d_in[o + 6],  (const float*)d_in[o + 7],
            (const float*)d_in[o + 8],  (const float*)d_in[o + 9],
            (const float*)d_in[o + 10], (const float*)d_in[o + 11],
            out + (int64_t)(2 * m) * MAT,
            out + (int64_t)(2 * m + 1) * MAT);
    }
}

// Round 2
// 1411.366 us; speedup vs baseline: 1.8222x; 1.8222x over previous
//
#include <hip/hip_runtime.h>
#include <cstdint>

#define HID2 128
#define CSZ  144
#define PITCH 148   // multiple of 4 (16B-aligned rows for ds_read_b128), 148/4=37 ≡ 5 mod 32 -> conflict-free column reads

// 4 waves / block, 64 rows / block. Wave w handles output-dim quarter w.
// Weight indices are wave-uniform -> scalar (SGPR) loads; activations per-lane in LDS.
__global__ __launch_bounds__(256, 4)
void mmse_mlp(const float* __restrict__ xr, const float* __restrict__ xi,
              const float* __restrict__ W1, const float* __restrict__ b1,
              const float* __restrict__ g1, const float* __restrict__ be1,
              const float* __restrict__ W2, const float* __restrict__ b2,
              const float* __restrict__ g2, const float* __restrict__ be2,
              const float* __restrict__ W3, const float* __restrict__ b3,
              const float* __restrict__ W4, const float* __restrict__ b4,
              float* __restrict__ outLr, float* __restrict__ outLi)
{
    __shared__ float hb[64][PITCH];   // x / h1 / h2 / h3 / f staging (37.9 KB)
    __shared__ float red[64][9];      // LN partials: [row][wave*2 + {s,s2}], pad 9 -> conflict-free

    const int tid  = threadIdx.x;
    const int lane = tid & 63;
    const int w    = __builtin_amdgcn_readfirstlane(tid >> 6);  // wave-uniform 0..3
    const int64_t rowg = (int64_t)blockIdx.x * 64 + lane;

    // ---- stage x = concat(real, imag) into hb[lane][0..23] (wave 0 only, tiny) ----
    if (w == 0) {
        const float4* pr = reinterpret_cast<const float4*>(xr + rowg * 12);
        const float4* pi = reinterpret_cast<const float4*>(xi + rowg * 12);
        #pragma unroll
        for (int c = 0; c < 3; ++c) {
            float4 v = pr[c];
            hb[lane][4*c+0] = v.x; hb[lane][4*c+1] = v.y;
            hb[lane][4*c+2] = v.z; hb[lane][4*c+3] = v.w;
        }
        #pragma unroll
        for (int c = 0; c < 3; ++c) {
            float4 v = pi[c];
            hb[lane][12+4*c+0] = v.x; hb[lane][12+4*c+1] = v.y;
            hb[lane][12+4*c+2] = v.z; hb[lane][12+4*c+3] = v.w;
        }
    }
    __syncthreads();

    float acc[36];  // widest per-wave chunk (layer4: 144/4 = 36)

    // ---------------- layer 1: 24 -> 128, LN, lrelu ----------------
    {
        const int jb = w * 32;
        #pragma unroll
        for (int j = 0; j < 32; ++j) acc[j] = b1[jb + j];
        #pragma unroll 4
        for (int k = 0; k < 24; ++k) {
            const float hk = hb[lane][k];
            const float* __restrict__ wr = W1 + k * HID2 + jb;   // uniform addr
            #pragma unroll
            for (int j = 0; j < 32; ++j) acc[j] = fmaf(hk, wr[j], acc[j]);
        }
        float s = 0.f, s2 = 0.f;
        #pragma unroll
        for (int j = 0; j < 32; ++j) { s += acc[j]; s2 += acc[j] * acc[j]; }
        red[lane][w*2+0] = s; red[lane][w*2+1] = s2;
        __syncthreads();   // also guarantees all k-loop reads of hb (x) are done
        s  = red[lane][0] + red[lane][2] + red[lane][4] + red[lane][6];
        s2 = red[lane][1] + red[lane][3] + red[lane][5] + red[lane][7];
        const float mean = s * (1.f / 128.f);
        const float var  = s2 * (1.f / 128.f) - mean * mean;
        const float rstd = 1.f / sqrtf(var + 1e-5f);
        #pragma unroll
        for (int j = 0; j < 32; ++j) {
            float h = (acc[j] - mean) * rstd * g1[jb + j] + be1[jb + j];
            h = (h >= 0.f) ? h : 0.1f * h;
            hb[lane][jb + j] = h;
        }
        __syncthreads();
    }

    // ---------------- layer 2: 128 -> 128, LN, lrelu ----------------
    {
        const int jb = w * 32;
        #pragma unroll
        for (int j = 0; j < 32; ++j) acc[j] = b2[jb + j];
        #pragma unroll 4
        for (int k = 0; k < 128; ++k) {
            const float hk = hb[lane][k];
            const float* __restrict__ wr = W2 + k * HID2 + jb;
            #pragma unroll
            for (int j = 0; j < 32; ++j) acc[j] = fmaf(hk, wr[j], acc[j]);
        }
        float s = 0.f, s2 = 0.f;
        #pragma unroll
        for (int j = 0; j < 32; ++j) { s += acc[j]; s2 += acc[j] * acc[j]; }
        red[lane][w*2+0] = s; red[lane][w*2+1] = s2;
        __syncthreads();   // k-loop reads of h1 done everywhere
        s  = red[lane][0] + red[lane][2] + red[lane][4] + red[lane][6];
        s2 = red[lane][1] + red[lane][3] + red[lane][5] + red[lane][7];
        const float mean = s * (1.f / 128.f);
        const float var  = s2 * (1.f / 128.f) - mean * mean;
        const float rstd = 1.f / sqrtf(var + 1e-5f);
        #pragma unroll
        for (int j = 0; j < 32; ++j) {
            float h = (acc[j] - mean) * rstd * g2[jb + j] + be2[jb + j];
            h = (h >= 0.f) ? h : 0.1f * h;
            hb[lane][jb + j] = h;
        }
        __syncthreads();
    }

    // ---------------- layer 3: 128 -> 64, lrelu ----------------
    {
        const int jb = w * 16;
        #pragma unroll
        for (int j = 0; j < 16; ++j) acc[j] = b3[jb + j];
        #pragma unroll 4
        for (int k = 0; k < 128; ++k) {
            const float hk = hb[lane][k];
            const float* __restrict__ wr = W3 + k * 64 + jb;
            #pragma unroll
            for (int j = 0; j < 16; ++j) acc[j] = fmaf(hk, wr[j], acc[j]);
        }
        __syncthreads();   // everyone done reading h2
        #pragma unroll
        for (int j = 0; j < 16; ++j) {
            float h = acc[j];
            h = (h >= 0.f) ? h : 0.1f * h;
            hb[lane][jb + j] = h;
        }
        __syncthreads();
    }

    // ---------------- layer 4: 64 -> 144 ----------------
    {
        const int jb = w * 36;
        #pragma unroll
        for (int j = 0; j < 36; ++j) acc[j] = b4[jb + j];
        #pragma unroll 4
        for (int k = 0; k < 64; ++k) {
            const float hk = hb[lane][k];
            const float* __restrict__ wr = W4 + k * CSZ + jb;
            #pragma unroll
            for (int j = 0; j < 36; ++j) acc[j] = fmaf(hk, wr[j], acc[j]);
        }
        __syncthreads();   // everyone done reading h3
        #pragma unroll
        for (int j = 0; j < 36; ++j) hb[lane][jb + j] = acc[j];  // stage f[144]
        __syncthreads();
    }

    // ---------------- build L (Lr, Li) and write coalesced ----------------
    {
        const int64_t base = (int64_t)blockIdx.x * 64 * CSZ;
        #pragma unroll
        for (int mat = 0; mat < 2; ++mat) {
            float* __restrict__ op = (mat == 0) ? (outLr + base) : (outLi + base);
            const int ob = (mat == 0) ? 12 : 78;   // strict-lower factor base
            #pragma unroll
            for (int u = 0; u < 9; ++u) {
                const int t4 = tid + u * 256;        // 0..2303 float4 units
                const int r  = t4 / 36;              // row within block
                const int cc = (t4 - r * 36) * 4;    // column (0..143)
                float vv[4];
                #pragma unroll
                for (int e = 0; e < 4; ++e) {
                    const int c = cc + e;
                    const int i = c / 12;
                    const int j = c - i * 12;
                    float val = 0.f;
                    if (i > j)                       val = hb[r][ob + (i * (i - 1)) / 2 + j];
                    else if (i == j && mat == 0)     val = hb[r][i];   // Lr diag
                    vv[e] = val;
                }
                float4 v; v.x = vv[0]; v.y = vv[1]; v.z = vv[2]; v.w = vv[3];
                reinterpret_cast<float4*>(op)[t4] = v;
            }
        }
    }
}

extern "C" void kernel_launch(void* const* d_in, const int* in_sizes, int n_in,
                              void* d_out, int out_size, void* d_ws, size_t ws_size,
                              hipStream_t stream)
{
    const float* xr = (const float*)d_in[0];
    const float* xi = (const float*)d_in[1];
    float* out = (float*)d_out;
    const int64_t MAT = (int64_t)262144 * CSZ;

    for (int m = 0; m < 2; ++m) {        // m=0: C-MLP (mats 0,1), m=1: R-MLP (mats 2,3)
        const int o = 2 + m * 12;
        mmse_mlp<<<4096, 256, 0, stream>>>(
            xr, xi,
            (const float*)d_in[o + 0],  (const float*)d_in[o + 1],
            (const float*)d_in[o + 2],  (const float*)d_in[o + 3],
            (const float*)d_in[o + 4],  (const float*)d_in[o + 5],
            (const float*)d_in[o + 6],  (const float*)d_in[o + 7],
            (const float*)d_in[o + 8],  (const float*)d_in[o + 9],
            (const float*)d_in[o + 10], (const float*)d_in[o + 11],
            out + (int64_t)(2 * m) * MAT,
            out + (int64_t)(2 * m + 1) * MAT);
    }
}

// Round 4
// 1072.652 us; speedup vs baseline: 2.3976x; 1.3158x over previous
//
#include <hip/hip_runtime.h>
#include <cstdint>

#define HID2 128
#define CSZ  144
#define TPITCH 65   // transposed row pitch (floats); lane-stride is 1 float -> conflict-free

// 8 waves / block, 64 rows / block. Wave w handles output-dim eighth w.
// LDS holds activations TRANSPOSED: hbT[dim][row]. Hot reads hbT[k][lane] have
// lane-stride 4B (2 lanes/bank = free). LN partials overlay hbT rows 128..143
// (dead until the f-stage). Weights/bias/gamma/beta are wave-uniform -> SGPR loads.
__global__ __launch_bounds__(512, 8)
void mmse_mlp(const float* __restrict__ xr, const float* __restrict__ xi,
              const float* __restrict__ W1, const float* __restrict__ b1,
              const float* __restrict__ g1, const float* __restrict__ be1,
              const float* __restrict__ W2, const float* __restrict__ b2,
              const float* __restrict__ g2, const float* __restrict__ be2,
              const float* __restrict__ W3, const float* __restrict__ b3,
              const float* __restrict__ W4, const float* __restrict__ b4,
              float* __restrict__ outLr, float* __restrict__ outLi)
{
    __shared__ float hbT[CSZ][TPITCH];   // 144*65*4 = 37.4 KB -> 4 blocks/CU

    const int tid  = threadIdx.x;
    const int lane = tid & 63;                                   // row within block
    const int w    = __builtin_amdgcn_readfirstlane(tid >> 6);   // wave-uniform 0..7
    const int64_t rowbase = (int64_t)blockIdx.x * 64;

    // LN partial buffer overlaid on hbT rows 128..143 (1024 floats = 8 waves * 64 rows * {s,s2})
    float2* red2 = reinterpret_cast<float2*>(&hbT[128][0]);

    // ---- stage x transposed: waves 0-2 load real, waves 4-6 load imag ----
    if (tid < 192) {
        const int r = tid / 3, s = tid % 3;
        const float4 v = reinterpret_cast<const float4*>(xr + (rowbase + r) * 12)[s];
        hbT[4*s+0][r] = v.x; hbT[4*s+1][r] = v.y; hbT[4*s+2][r] = v.z; hbT[4*s+3][r] = v.w;
    } else if (tid >= 256 && tid < 448) {
        const int t = tid - 256;
        const int r = t / 3, s = t % 3;
        const float4 v = reinterpret_cast<const float4*>(xi + (rowbase + r) * 12)[s];
        hbT[12+4*s+0][r] = v.x; hbT[12+4*s+1][r] = v.y; hbT[12+4*s+2][r] = v.z; hbT[12+4*s+3][r] = v.w;
    }
    __syncthreads();

    float acc[18];   // widest per-wave chunk (layer4: 144/8 = 18)

    // ---------------- layer 1: 24 -> 128, LN, lrelu ----------------
    {
        const int jb = w * 16;
        #pragma unroll
        for (int j = 0; j < 16; ++j) acc[j] = b1[jb + j];
        #pragma unroll 4
        for (int k = 0; k < 24; ++k) {
            const float hk = hbT[k][lane];
            const float* __restrict__ wr = W1 + k * HID2 + jb;   // uniform addr -> s_load
            #pragma unroll
            for (int j = 0; j < 16; ++j) acc[j] = fmaf(hk, wr[j], acc[j]);
        }
        float s = 0.f, s2 = 0.f;
        #pragma unroll
        for (int j = 0; j < 16; ++j) { s += acc[j]; s2 += acc[j] * acc[j]; }
        float2 p; p.x = s; p.y = s2;
        red2[w * 64 + lane] = p;
        __syncthreads();                       // x reads + red writes complete
        s = 0.f; s2 = 0.f;
        #pragma unroll
        for (int i = 0; i < 8; ++i) { float2 v = red2[i * 64 + lane]; s += v.x; s2 += v.y; }
        const float mean = s * (1.f / 128.f);
        const float var  = s2 * (1.f / 128.f) - mean * mean;
        const float rstd = 1.f / sqrtf(var + 1e-5f);
        #pragma unroll
        for (int j = 0; j < 16; ++j) {
            float h = (acc[j] - mean) * rstd * g1[jb + j] + be1[jb + j];
            h = (h >= 0.f) ? h : 0.1f * h;
            hbT[jb + j][lane] = h;             // rows 0..127 (x dead)
        }
        __syncthreads();
    }

    // ---------------- layer 2: 128 -> 128, LN, lrelu ----------------
    {
        const int jb = w * 16;
        #pragma unroll
        for (int j = 0; j < 16; ++j) acc[j] = b2[jb + j];
        #pragma unroll 4
        for (int k = 0; k < 128; ++k) {
            const float hk = hbT[k][lane];
            const float* __restrict__ wr = W2 + k * HID2 + jb;
            #pragma unroll
            for (int j = 0; j < 16; ++j) acc[j] = fmaf(hk, wr[j], acc[j]);
        }
        float s = 0.f, s2 = 0.f;
        #pragma unroll
        for (int j = 0; j < 16; ++j) { s += acc[j]; s2 += acc[j] * acc[j]; }
        float2 p; p.x = s; p.y = s2;
        red2[w * 64 + lane] = p;               // rows 128..143, not read by k-loop
        __syncthreads();                       // h1 reads + red writes complete
        s = 0.f; s2 = 0.f;
        #pragma unroll
        for (int i = 0; i < 8; ++i) { float2 v = red2[i * 64 + lane]; s += v.x; s2 += v.y; }
        const float mean = s * (1.f / 128.f);
        const float var  = s2 * (1.f / 128.f) - mean * mean;
        const float rstd = 1.f / sqrtf(var + 1e-5f);
        #pragma unroll
        for (int j = 0; j < 16; ++j) {
            float h = (acc[j] - mean) * rstd * g2[jb + j] + be2[jb + j];
            h = (h >= 0.f) ? h : 0.1f * h;
            hbT[jb + j][lane] = h;             // h2 over h1 (dead after sync)
        }
        __syncthreads();
    }

    // ---------------- layer 3: 128 -> 64, lrelu ----------------
    {
        const int jb = w * 8;
        #pragma unroll
        for (int j = 0; j < 8; ++j) acc[j] = b3[jb + j];
        #pragma unroll 4
        for (int k = 0; k < 128; ++k) {
            const float hk = hbT[k][lane];
            const float* __restrict__ wr = W3 + k * 64 + jb;
            #pragma unroll
            for (int j = 0; j < 8; ++j) acc[j] = fmaf(hk, wr[j], acc[j]);
        }
        __syncthreads();                       // everyone done reading h2
        #pragma unroll
        for (int j = 0; j < 8; ++j) {
            float h = acc[j];
            h = (h >= 0.f) ? h : 0.1f * h;
            hbT[jb + j][lane] = h;             // h3 rows 0..63
        }
        __syncthreads();
    }

    // ---------------- layer 4: 64 -> 144 ----------------
    {
        const int jb = w * 18;
        #pragma unroll
        for (int j = 0; j < 18; ++j) acc[j] = b4[jb + j];
        #pragma unroll 4
        for (int k = 0; k < 64; ++k) {
            const float hk = hbT[k][lane];
            const float* __restrict__ wr = W4 + k * CSZ + jb;
            #pragma unroll
            for (int j = 0; j < 18; ++j) acc[j] = fmaf(hk, wr[j], acc[j]);
        }
        __syncthreads();                       // everyone done reading h3
        #pragma unroll
        for (int j = 0; j < 18; ++j) hbT[jb + j][lane] = acc[j];   // f rows 0..143
        __syncthreads();
    }

    // ---------------- build L (Lr, Li), write coalesced float4 ----------------
    {
        const int64_t base = (int64_t)blockIdx.x * 64 * CSZ;
        #pragma unroll
        for (int mat = 0; mat < 2; ++mat) {
            float* __restrict__ op = (mat == 0) ? (outLr + base) : (outLi + base);
            const int ob = (mat == 0) ? 12 : 78;   // strict-lower factor base
            #pragma unroll
            for (int u = 0; u < 5; ++u) {
                const int t4 = tid + u * 512;        // 0..2303 float4 units
                if (t4 < 2304) {
                    const int r  = t4 / 36;              // row within block
                    const int cc = (t4 - r * 36) * 4;    // column (0..143)
                    float vv[4];
                    #pragma unroll
                    for (int e = 0; e < 4; ++e) {
                        const int c = cc + e;
                        const int i = c / 12;
                        const int j = c - i * 12;
                        float val = 0.f;
                        if (i > j)                       val = hbT[ob + (i * (i - 1)) / 2 + j][r];
                        else if (i == j && mat == 0)     val = hbT[i][r];   // Lr diag
                        vv[e] = val;
                    }
                    float4 v; v.x = vv[0]; v.y = vv[1]; v.z = vv[2]; v.w = vv[3];
                    reinterpret_cast<float4*>(op)[t4] = v;
                }
            }
        }
    }
}

extern "C" void kernel_launch(void* const* d_in, const int* in_sizes, int n_in,
                              void* d_out, int out_size, void* d_ws, size_t ws_size,
                              hipStream_t stream)
{
    const float* xr = (const float*)d_in[0];
    const float* xi = (const float*)d_in[1];
    float* out = (float*)d_out;
    const int64_t MAT = (int64_t)262144 * CSZ;

    for (int m = 0; m < 2; ++m) {        // m=0: C-MLP (mats 0,1), m=1: R-MLP (mats 2,3)
        const int o = 2 + m * 12;
        mmse_mlp<<<4096, 512, 0, stream>>>(
            xr, xi,
            (const float*)d_in[o + 0],  (const float*)d_in[o + 1],
            (const float*)d_in[o + 2],  (const float*)d_in[o + 3],
            (const float*)d_in[o + 4],  (const float*)d_in[o + 5],
            (const float*)d_in[o + 6],  (const float*)d_in[o + 7],
            (const float*)d_in[o + 8],  (const float*)d_in[o + 9],
            (const float*)d_in[o + 10], (const float*)d_in[o + 11],
            out + (int64_t)(2 * m) * MAT,
            out + (int64_t)(2 * m + 1) * MAT);
    }
}